// Round 1
// baseline (177.703 us; speedup 1.0000x reference)
//
#include <hip/hip_runtime.h>

#define B_N 4096
#define S_N 200
#define E_N 32

typedef float f32x4 __attribute__((ext_vector_type(4)));
typedef short s16x8 __attribute__((ext_vector_type(8)));

// f32 -> bf16 with round-to-nearest-even, as raw u16 bits
static __device__ __forceinline__ unsigned short f2bf(float f) {
    unsigned u = __builtin_bit_cast(unsigned, f);
    u += 0x7fffu + ((u >> 16) & 1u);
    return (unsigned short)(u >> 16);
}

__global__ __launch_bounds__(256, 4) void attn_pool_kernel(
    const float* __restrict__ am,    // [B,S,E]
    const float* __restrict__ lastm, // [B,E]
    const float* __restrict__ avgm,  // [B,E]
    const float* __restrict__ W1,    // [E,E]
    const float* __restrict__ b1,    // [E]
    const float* __restrict__ W2,    // [E,E]
    const float* __restrict__ b2,    // [E]
    const float* __restrict__ W3,    // [E,E]
    const float* __restrict__ b3,    // [E]
    const float* __restrict__ W4,    // [E,1]
    float* __restrict__ out)         // [B,E]
{
    const int tid  = threadIdx.x;
    const int l    = tid & 63;           // lane in wave
    const int wave = tid >> 6;
    const int b    = blockIdx.x * 4 + wave;

    const int lm = l & 15;   // 0..15 : row-slot / col
    const int lg = l >> 4;   // 0..3  : k-slice group
    const int fi = l & 31;   // f index for base computation (lanes 32-63 duplicate)

    // ---- base[f] = b1[f]+b2[f]+b3[f] + (last@W2)[f] + (avg@W3)[f], at lane f=fi ----
    float lastv = lastm[b * E_N + fi];
    float avgv  = avgm [b * E_N + fi];
    float base_f = b1[fi] + b2[fi] + b3[fi];
#pragma unroll
    for (int e = 0; e < E_N; ++e) {
        float le = __shfl(lastv, e);
        float ae = __shfl(avgv,  e);
        base_f += le * W2[e * E_N + fi] + ae * W3[e * E_N + fi];
    }
    // redistribute to MFMA-D layout: this lane's two f-columns are lm and 16+lm
    float baseA = __shfl(base_f, lm);
    float baseB = __shfl(base_f, 16 + lm);
    float w4A = W4[lm];
    float w4B = W4[16 + lm];

    // ---- W1 B-fragments (K=32 x N=16, lane: n=lm, k=8*lg+i) ----
    s16x8 bfA, bfB;
#pragma unroll
    for (int i = 0; i < 8; ++i) {
        int k = 8 * lg + i;
        bfA[i] = (short)f2bf(W1[k * E_N + lm]);
        bfB[i] = (short)f2bf(W1[k * E_N + 16 + lm]);
    }

    float acc[8];
#pragma unroll
    for (int i = 0; i < 8; ++i) acc[i] = 0.0f;

    const int e0 = 8 * lg;  // this lane's e-slice for A / PV

    for (int t = 0; t < 13; ++t) {
        const int r = t * 16 + lm;   // row of am this lane loads
        float amf[8];
        if (r < S_N) {
            const f32x4* p = (const f32x4*)(am + ((size_t)b * S_N + r) * E_N + e0);
            f32x4 v0 = p[0];
            f32x4 v1 = p[1];
#pragma unroll
            for (int i = 0; i < 4; ++i) { amf[i] = v0[i]; amf[4 + i] = v1[i]; }
        } else {
#pragma unroll
            for (int i = 0; i < 8; ++i) amf[i] = 0.0f;
        }

        // A fragment: row=lm, k=e0+i
        s16x8 af;
#pragma unroll
        for (int i = 0; i < 8; ++i) af[i] = (short)f2bf(amf[i]);

        f32x4 z = {0.0f, 0.0f, 0.0f, 0.0f};
        f32x4 d0 = __builtin_amdgcn_mfma_f32_16x16x32_bf16(af, bfA, z, 0, 0, 0);
        f32x4 d1 = __builtin_amdgcn_mfma_f32_16x16x32_bf16(af, bfB, z, 0, 0, 0);

        // sc[j]: partial score for row t*16 + 4*lg + j (this lane's 2 f-cols)
        float sc[4];
#pragma unroll
        for (int j = 0; j < 4; ++j) {
            float pA = d0[j] + baseA;
            float pB = d1[j] + baseB;
            float sA = 1.0f / (1.0f + __expf(-pA));
            float sB = 1.0f / (1.0f + __expf(-pB));
            sc[j] = sA * w4A + sB * w4B;
        }
        // reduce over the 16 f-columns (lanes within 16-group)
#pragma unroll
        for (int j = 0; j < 4; ++j) {
            sc[j] += __shfl_xor(sc[j], 1);
            sc[j] += __shfl_xor(sc[j], 2);
            sc[j] += __shfl_xor(sc[j], 4);
            sc[j] += __shfl_xor(sc[j], 8);
        }
        // fetch the score for MY loaded row r = t*16 + lm:
        // it lives in group lm>>2, register slot lm&3
        const int src = (lm >> 2) << 4;
        float t0 = __shfl(sc[0], src);
        float t1 = __shfl(sc[1], src);
        float t2 = __shfl(sc[2], src);
        float t3 = __shfl(sc[3], src);
        const int jj = lm & 3;
        float score = (jj == 0) ? t0 : (jj == 1) ? t1 : (jj == 2) ? t2 : t3;

        // PV accumulate in f32 (amf kept exact)
#pragma unroll
        for (int i = 0; i < 8; ++i) acc[i] += score * amf[i];
    }

    // sum over the 16 row-slots within each e-slice group
#pragma unroll
    for (int i = 0; i < 8; ++i) {
        acc[i] += __shfl_xor(acc[i], 1);
        acc[i] += __shfl_xor(acc[i], 2);
        acc[i] += __shfl_xor(acc[i], 4);
        acc[i] += __shfl_xor(acc[i], 8);
    }
    if (lm == 0) {
        f32x4 o0, o1;
#pragma unroll
        for (int i = 0; i < 4; ++i) { o0[i] = acc[i]; o1[i] = acc[4 + i]; }
        f32x4* po = (f32x4*)(out + (size_t)b * E_N + e0);
        po[0] = o0;
        po[1] = o1;
    }
}

extern "C" void kernel_launch(void* const* d_in, const int* in_sizes, int n_in,
                              void* d_out, int out_size, void* d_ws, size_t ws_size,
                              hipStream_t stream) {
    const float* am    = (const float*)d_in[0];
    const float* lastm = (const float*)d_in[1];
    const float* avgm  = (const float*)d_in[2];
    // d_in[3] = mask: dead code in the reference (only used when mask is None)
    const float* W1 = (const float*)d_in[4];
    const float* b1 = (const float*)d_in[5];
    const float* W2 = (const float*)d_in[6];
    const float* b2 = (const float*)d_in[7];
    const float* W3 = (const float*)d_in[8];
    const float* b3 = (const float*)d_in[9];
    const float* W4 = (const float*)d_in[10];
    float* out = (float*)d_out;

    dim3 grid(B_N / 4);   // 4 waves per block, 1 batch row per wave
    dim3 block(256);
    hipLaunchKernelGGL(attn_pool_kernel, grid, block, 0, stream,
                       am, lastm, avgm, W1, b1, W2, b2, W3, b3, W4, out);
}